// Round 3
// baseline (960.468 us; speedup 1.0000x reference)
//
#include <hip/hip_runtime.h>

// ---------------------------------------------------------------------------
// NewCNNEncoder: one-hot(x[B,25]) -> {full, hori, vert} branches -> cat[B,960]
//                -> big GEMM [B,960]x[960,1600] -> lrelu -> out fp32.
//
// Decomposition:
//  P   prep_kernel   : bf16-transpose/permute W_out & W_pf; build U tables
//  A   build_afull   : a_full[B,448] = lrelu(depthwise_full + b_df)  (bf16)
//  G1  gemm_bt<448,0>: cat[:,0:320]  = lrelu(a_full @ W_pf^T + b_pf) (bf16 MFMA)
//  HV  hv_kernel     : cat[:,320:960] via U-table lookups (exact fp32 math)
//  G2  gemm_bt<960,1>: out = lrelu(cat @ W_out'^T + b_out)           (bf16 MFMA)
//
// R1/R2: chunk-contiguous XCD swizzle (T1). FETCH 1.02GB -> 267MB (A ~8x -> ~2x),
//        G2 415 -> 357 us. Now latency-bound: all pipes <35% busy.
// R3: depth-2 pipelined K-loop (T3+T4-lite): 3 LDS buffers, prefetch tile t+2
//     before computing tile t, raw s_barrier + counted s_waitcnt vmcnt(4)
//     (vmcnt(0) only on the final drain). Removes the per-K-step full
//     vmcnt(0) drain that exposed A/B load latency every iteration.
// ---------------------------------------------------------------------------

typedef __bf16 bf16;
typedef bf16  bf16x8 __attribute__((ext_vector_type(8)));
typedef float f32x4  __attribute__((ext_vector_type(4)));

__device__ __forceinline__ float lrelu(float v) { return v > 0.f ? v : 0.01f * v; }

// async global->LDS, 16B per lane; LDS dest must be wave-uniform base + lane*16
__device__ __forceinline__ void gl2lds16(const void* g, void* l) {
  __builtin_amdgcn_global_load_lds(
      (__attribute__((address_space(1))) void*)const_cast<void*>(g),
      (__attribute__((address_space(3))) void*)l, 16, 0, 0);
}

// T1 chunk-contiguous XCD swizzle (m204 bijective form).
__device__ __forceinline__ void xcd_remap(int& mt, int& nt) {
  const int nxt    = gridDim.x;
  const int nwg    = gridDim.x * gridDim.y;
  const int linear = blockIdx.y * gridDim.x + blockIdx.x;
  const int xcd = linear & 7, pos = linear >> 3;
  const int q = nwg >> 3, r = nwg & 7;
  const int logical = (xcd < r ? xcd * (q + 1) : r * (q + 1) + (xcd - r) * q) + pos;
  mt = logical / nxt;
  nt = logical - mt * nxt;
}

// ---------------------------------------------------------------------------
// Prep: weight conversion + U tables
// ---------------------------------------------------------------------------
__device__ void compute_U(float* __restrict__ U,
                          const float* __restrict__ Wd, const float* __restrict__ bd,
                          const float* __restrict__ Wp, const float* __restrict__ bp,
                          int c, int mask, int o) {
  float val;
  if (mask == 0) {
    if (c == 0) {  // base[o] = bp[o] + sum_cc sum_m Wp[o,cc*16+m]*lrelu(bd)
      float s = bp[o];
      for (int cc = 0; cc < 17; cc++)
        for (int m = 0; m < 16; m++)
          s += Wp[o * 272 + cc * 16 + m] * lrelu(bd[cc * 16 + m]);
      val = s;
    } else {
      val = 0.f;
    }
  } else {
    float s = 0.f;
    #pragma unroll
    for (int m = 0; m < 16; m++) {
      float z = bd[c * 16 + m];
      #pragma unroll
      for (int j = 0; j < 5; j++)
        if ((mask >> j) & 1) z += Wd[c * 80 + m * 5 + j];
      s += Wp[o * 272 + c * 16 + m] * (lrelu(z) - lrelu(bd[c * 16 + m]));
    }
    val = s;
  }
  U[(c * 32 + mask) * 64 + o] = val;
}

__global__ __launch_bounds__(256) void prep_kernel(
    const float* __restrict__ W_pf,
    const float* __restrict__ W_dh, const float* __restrict__ b_dh,
    const float* __restrict__ W_ph, const float* __restrict__ b_ph,
    const float* __restrict__ W_dv, const float* __restrict__ b_dv,
    const float* __restrict__ W_pv, const float* __restrict__ b_pv,
    const float* __restrict__ W_out,
    bf16* __restrict__ WbOT, bf16* __restrict__ WbPF,
    float* __restrict__ Uh, float* __restrict__ Uv) {
  int id = blockIdx.x * 256 + threadIdx.x;

  if (id < 1664 * 960) {  // WbOT[n][k]
    int n = id / 960, k = id % 960;
    float v = 0.f;
    if (n < 1600) {
      int src;
      if (k < 320)      src = n * 960 + (k / 5) * 15 + (k % 5);            // full
      else if (k < 640) { int kk = k - 320; src = n * 960 + (kk & 63) * 15 + 5  + (kk >> 6); }  // hori
      else              { int kk = k - 640; src = n * 960 + (kk & 63) * 15 + 10 + (kk >> 6); }  // vert
      v = W_out[src];
    }
    WbOT[id] = (bf16)v;
    return;
  }
  id -= 1664 * 960;

  if (id < 384 * 448) {  // WbPF[n][k]
    int n = id / 448, k = id % 448;
    float v = (n < 320 && k < 425) ? W_pf[n * 425 + k] : 0.f;
    WbPF[id] = (bf16)v;
    return;
  }
  id -= 384 * 448;

  if (id < 17 * 32 * 64) {
    int o = id & 63, rest = id >> 6;
    compute_U(Uh, W_dh, b_dh, W_ph, b_ph, rest >> 5, rest & 31, o);
    return;
  }
  id -= 17 * 32 * 64;

  if (id < 17 * 32 * 64) {
    int o = id & 63, rest = id >> 6;
    compute_U(Uv, W_dv, b_dv, W_pv, b_pv, rest >> 5, rest & 31, o);
  }
}

// ---------------------------------------------------------------------------
// build_afull
// ---------------------------------------------------------------------------
#define AF_PAD 456  // LDS row stride (bf16 elems); 456 -> 8-way max bank conflict

__global__ __launch_bounds__(256) void build_afull(
    const int* __restrict__ x, const float* __restrict__ W_df,
    const float* __restrict__ b_df, bf16* __restrict__ a_full) {
  __shared__ int  xs[64 * 25];
  __shared__ bf16 as[64 * AF_PAD];
  const int b0 = blockIdx.x * 64;
  for (int i = threadIdx.x; i < 64 * 25; i += 256) xs[i] = x[(long)b0 * 25 + i];
  __syncthreads();

  const int wave = threadIdx.x >> 6, lane = threadIdx.x & 63;
  for (int role = wave; role < 18; role += 4) {
    if (role < 17) {
      const int c = role;
      float acc[25];
      #pragma unroll
      for (int m = 0; m < 25; m++) acc[m] = 0.f;
      #pragma unroll
      for (int l = 0; l < 25; l++) {
        int xl = xs[lane * 25 + l];
        if (xl == c) {
          #pragma unroll
          for (int m = 0; m < 25; m++) acc[m] += W_df[c * 625 + m * 25 + l];
        }
      }
      #pragma unroll
      for (int m = 0; m < 25; m++)
        as[lane * AF_PAD + c * 25 + m] = (bf16)lrelu(acc[m] + b_df[c * 25 + m]);
    } else {
      for (int k = 425; k < 448; k++) as[lane * AF_PAD + k] = (bf16)0.f;
    }
  }
  __syncthreads();

  // coalesced copy-out: 64 rows x 448 bf16 = 3584 x int4
  int4* dst = (int4*)(a_full + (long)b0 * 448);
  for (int i = threadIdx.x; i < 3584; i += 256) {
    int row = i / 56, off = i % 56;  // 56 int4 per row
    dst[i] = *(const int4*)((const char*)as + row * (AF_PAD * 2) + off * 16);
  }
}

// ---------------------------------------------------------------------------
// hv_kernel
// ---------------------------------------------------------------------------
__device__ __forceinline__ float group5(const float* __restrict__ U, int lane,
                                        int c0, int c1, int c2, int c3, int c4) {
  float acc = U[lane];  // base slot [0][0][lane]
  {
    int m = 1 | ((int)(c1 == c0) << 1) | ((int)(c2 == c0) << 2) |
                ((int)(c3 == c0) << 3) | ((int)(c4 == c0) << 4);
    acc += U[(c0 * 32 + m) * 64 + lane];
  }
  if (c1 != c0) {
    int m = 2 | ((int)(c2 == c1) << 2) | ((int)(c3 == c1) << 3) | ((int)(c4 == c1) << 4);
    acc += U[(c1 * 32 + m) * 64 + lane];
  }
  if (c2 != c0 && c2 != c1) {
    int m = 4 | ((int)(c3 == c2) << 3) | ((int)(c4 == c2) << 4);
    acc += U[(c2 * 32 + m) * 64 + lane];
  }
  if (c3 != c0 && c3 != c1 && c3 != c2) {
    int m = 8 | ((int)(c4 == c3) << 4);
    acc += U[(c3 * 32 + m) * 64 + lane];
  }
  if (c4 != c0 && c4 != c1 && c4 != c2 && c4 != c3) {
    acc += U[(c4 * 32 + 16) * 64 + lane];
  }
  return lrelu(acc);
}

__global__ __launch_bounds__(256) void hv_kernel(
    const int* __restrict__ x, const float* __restrict__ Uh,
    const float* __restrict__ Uv, bf16* __restrict__ cat) {
  const int wave = threadIdx.x >> 6, lane = threadIdx.x & 63;
  const long b = (long)blockIdx.x * 4 + wave;
  const int* xb = x + b * 25;
  int xv[25];
  #pragma unroll
  for (int i = 0; i < 25; i++) xv[i] = xb[i];
  bf16* catb = cat + b * 960;
  #pragma unroll
  for (int r = 0; r < 5; r++) {
    float v = group5(Uh, lane, xv[5*r], xv[5*r+1], xv[5*r+2], xv[5*r+3], xv[5*r+4]);
    catb[320 + r * 64 + lane] = (bf16)v;  // coalesced across lanes
  }
  #pragma unroll
  for (int j = 0; j < 5; j++) {
    float v = group5(Uv, lane, xv[j], xv[5+j], xv[10+j], xv[15+j], xv[20+j]);
    catb[640 + j * 64 + lane] = (bf16)v;
  }
}

// ---------------------------------------------------------------------------
// gemm_bt: C[M,N] = lrelu(A[M,KT] @ Bt[N,KT]^T + bias).
// 128x128 tile, BK=32, 4 waves x (4x4) 16x16x32 bf16 MFMA frags.
// R3: depth-2 pipeline, 3 LDS buffers, raw s_barrier + counted vmcnt.
//   iter kt: STAGE(kt+2 -> buf[(kt+2)%3]); ds_read+MFMA buf[kt%3];
//            s_waitcnt vmcnt(4)  (tile kt+1's 4 loads done; tile kt+2 in flight);
//            s_barrier; compiler-fence.
//   WAR safe: buf[(kt+2)%3] was last read in iter kt-1; those reads completed
//   (consumed by MFMA, lgkmcnt-waited) before that iter's barrier.
//   Cross-wave visibility: each wave stages its own 32-row slice and waits its
//   own vmcnt BEFORE the barrier -> after barrier all slices are resident.
// MODE 0: bf16 out (cat, G1).  MODE 1: f32 out (final, G2).
// ---------------------------------------------------------------------------
template <int KT, int MODE>
__global__ __launch_bounds__(256, 2) void gemm_bt(
    const bf16* __restrict__ A, const bf16* __restrict__ Bt,
    const float* __restrict__ bias, bf16* __restrict__ outb,
    float* __restrict__ outf, const int Nwrite, const int ldOut) {
  static_assert(KT % 32 == 0, "KT must be multiple of 32");
  constexpr int NT = KT / 32;
  static_assert(NT >= 3, "pipeline assumes at least 3 K-tiles");
  __shared__ bf16 As[3][128 * 32];
  __shared__ bf16 Bs[3][128 * 32];

  const int tid = threadIdx.x;
  const int wave = tid >> 6, lane = tid & 63;
  int mt, nt;
  xcd_remap(mt, nt);

  // staging: wave covers 32 rows (2 instrs of 16 rows); lane -> (row=lane/4, 16B chunk=lane%4)
  const int  lrow = lane >> 2, lcol = lane & 3;
  const bf16* ag0 = A  + ((long)mt * 128 + wave * 32 + lrow) * KT + lcol * 8;
  const bf16* bg0 = Bt + ((long)nt * 128 + wave * 32 + lrow) * KT + lcol * 8;
  const int lds_off = (wave * 32 + lrow) * 32 + lcol * 8;  // = wave base + lane*16B

  const int wm = (wave & 1) * 64;   // wave's 64x64 sub-tile
  const int wn = (wave >> 1) * 64;
  const int fr = lane & 15;         // frag row (A) / col (B)
  const int fq = lane >> 4;         // quad -> k chunk

  f32x4 acc[4][4];
  #pragma unroll
  for (int i = 0; i < 4; i++)
    #pragma unroll
    for (int j = 0; j < 4; j++) acc[i][j] = f32x4{0.f, 0.f, 0.f, 0.f};

  // ---- prologue: stage tiles 0 and 1, wait tile 0, barrier
  {
    gl2lds16(ag0 + 0,                 &As[0][lds_off]);
    gl2lds16(ag0 + 0 + (long)16 * KT, &As[0][lds_off + 16 * 32]);
    gl2lds16(bg0 + 0,                 &Bs[0][lds_off]);
    gl2lds16(bg0 + 0 + (long)16 * KT, &Bs[0][lds_off + 16 * 32]);
    gl2lds16(ag0 + 32,                 &As[1][lds_off]);
    gl2lds16(ag0 + 32 + (long)16 * KT, &As[1][lds_off + 16 * 32]);
    gl2lds16(bg0 + 32,                 &Bs[1][lds_off]);
    gl2lds16(bg0 + 32 + (long)16 * KT, &Bs[1][lds_off + 16 * 32]);
  }
  asm volatile("s_waitcnt vmcnt(4)" ::: "memory");  // tile 0 resident (own slice)
  __builtin_amdgcn_s_barrier();                     // all slices resident
  asm volatile("" ::: "memory");

  for (int kt = 0; kt < NT; kt++) {
    const int cur = kt % 3;
    // prefetch tile kt+2 into the buffer freed at end of iter kt-1
    if (kt + 2 < NT) {
      const int nxt2 = (kt + 2) % 3;
      const int ko = (kt + 2) * 32;
      gl2lds16(ag0 + ko,                 &As[nxt2][lds_off]);
      gl2lds16(ag0 + ko + (long)16 * KT, &As[nxt2][lds_off + 16 * 32]);
      gl2lds16(bg0 + ko,                 &Bs[nxt2][lds_off]);
      gl2lds16(bg0 + ko + (long)16 * KT, &Bs[nxt2][lds_off + 16 * 32]);
    }

    const bf16* Asb = As[cur];
    const bf16* Bsb = Bs[cur];
    bf16x8 af[4], bfv[4];
    #pragma unroll
    for (int i = 0; i < 4; i++)
      af[i] = *(const bf16x8*)&Asb[(wm + i * 16 + fr) * 32 + fq * 8];
    #pragma unroll
    for (int j = 0; j < 4; j++)
      bfv[j] = *(const bf16x8*)&Bsb[(wn + j * 16 + fr) * 32 + fq * 8];
    #pragma unroll
    for (int i = 0; i < 4; i++)
      #pragma unroll
      for (int j = 0; j < 4; j++)
        acc[i][j] = __builtin_amdgcn_mfma_f32_16x16x32_bf16(af[i], bfv[j], acc[i][j], 0, 0, 0);

    if (kt + 1 < NT) {
      if (kt + 2 < NT) {
        // outstanding: tile kt+1 (4) + tile kt+2 (4); wait until kt+1 done
        asm volatile("s_waitcnt vmcnt(4)" ::: "memory");
      } else {
        // no prefetch issued this iter: only tile kt+1's 4 remain -> drain
        asm volatile("s_waitcnt vmcnt(0)" ::: "memory");
      }
      __builtin_amdgcn_s_barrier();
      asm volatile("" ::: "memory");  // fence: keep next iter's ds_read below barrier
    }
  }

  // epilogue: D row = wm+i*16+fq*4+r, col = wn+j*16+fr
  #pragma unroll
  for (int j = 0; j < 4; j++) {
    const int n = nt * 128 + wn + j * 16 + fr;
    const bool ok = n < Nwrite;
    const float bv = ok ? bias[n] : 0.f;
    #pragma unroll
    for (int i = 0; i < 4; i++) {
      const long row0 = (long)mt * 128 + wm + i * 16 + fq * 4;
      #pragma unroll
      for (int r = 0; r < 4; r++) {
        float v = lrelu(acc[i][j][r] + bv);
        if (ok) {
          if (MODE == 0) outb[(row0 + r) * (long)ldOut + n] = (bf16)v;
          else           outf[(row0 + r) * (long)ldOut + n] = v;
        }
      }
    }
  }
}

// ---------------------------------------------------------------------------
extern "C" void kernel_launch(void* const* d_in, const int* in_sizes, int n_in,
                              void* d_out, int out_size, void* d_ws, size_t ws_size,
                              hipStream_t stream) {
  const int*   x     = (const int*)d_in[0];
  const float* W_df  = (const float*)d_in[1];
  const float* b_df  = (const float*)d_in[2];
  const float* W_pf  = (const float*)d_in[3];
  const float* b_pf  = (const float*)d_in[4];
  const float* W_dh  = (const float*)d_in[5];
  const float* b_dh  = (const float*)d_in[6];
  const float* W_ph  = (const float*)d_in[7];
  const float* b_ph  = (const float*)d_in[8];
  const float* W_dv  = (const float*)d_in[9];
  const float* b_dv  = (const float*)d_in[10];
  const float* W_pv  = (const float*)d_in[11];
  const float* b_pv  = (const float*)d_in[12];
  const float* W_out = (const float*)d_in[13];
  const float* b_out = (const float*)d_in[14];
  float* out = (float*)d_out;

  const int B = in_sizes[0] / 25;  // 65536

  char* ws = (char*)d_ws;
  size_t off = 0;
  bf16* cat   = (bf16*)(ws + off); off += (size_t)B * 960 * 2;
  bf16* afull = (bf16*)(ws + off); off += (size_t)B * 448 * 2;
  bf16* WbOT  = (bf16*)(ws + off); off += (size_t)1664 * 960 * 2;
  bf16* WbPF  = (bf16*)(ws + off); off += (size_t)384 * 448 * 2;
  float* Uh   = (float*)(ws + off); off += (size_t)17 * 32 * 64 * 4;
  float* Uv   = (float*)(ws + off); off += (size_t)17 * 32 * 64 * 4;

  const int prep_threads = 1664 * 960 + 384 * 448 + 2 * 17 * 32 * 64;
  prep_kernel<<<(prep_threads + 255) / 256, 256, 0, stream>>>(
      W_pf, W_dh, b_dh, W_ph, b_ph, W_dv, b_dv, W_pv, b_pv, W_out,
      WbOT, WbPF, Uh, Uv);

  build_afull<<<B / 64, 256, 0, stream>>>(x, W_df, b_df, afull);

  gemm_bt<448, 0><<<dim3(3, B / 128), 256, 0, stream>>>(
      afull, WbPF, b_pf, cat, nullptr, 320, 960);

  hv_kernel<<<B / 4, 256, 0, stream>>>(x, Uh, Uv, cat);

  gemm_bt<960, 1><<<dim3(13, B / 128), 256, 0, stream>>>(
      cat, WbOT, b_out, nullptr, out, 1600, 1600);
}